// Round 4
// baseline (1236.470 us; speedup 1.0000x reference)
//
#include <hip/hip_runtime.h>
#include <stdint.h>

typedef __bf16 bf16;
typedef __bf16 bf16x8 __attribute__((ext_vector_type(8)));
typedef float floatx4 __attribute__((ext_vector_type(4)));

#define LOG2E 1.44269504088896340736f

// ---------------- async global->LDS (16B/lane, wave-uniform LDS base) ----------------
__device__ __forceinline__ void gl2lds16(const bf16* g, bf16* l) {
    __builtin_amdgcn_global_load_lds((__attribute__((address_space(1))) void*)g,
                                     (__attribute__((address_space(3))) void*)l,
                                     16, 0, 0);
}

// chunk swizzle (16B chunks): spreads row-strided b128 reads across all 32 banks
template<int COLS>
__device__ __forceinline__ int swz(int ch, int r) {
    if constexpr (COLS == 32) return ch ^ ((r >> 1) & 3);
    else                      return ch ^ (r & 7);
}

// Stage ROWS x COLS bf16 tile into LDS, lane-contiguous dest, source chunk-swizzled.
template<int ROWS, int COLS>
__device__ __forceinline__ void stage_tile_sw(bf16* lds, const bf16* g, int srcStride, int wave, int lane) {
    constexpr int NINST = (ROWS * COLS * 2) / 1024;
    constexpr int ROWB  = COLS * 2;
    #pragma unroll
    for (int u = 0; u < NINST / 4; ++u) {
        int t  = wave + u * 4;
        int ob = t * 1024 + lane * 16;
        int r  = ob / ROWB;
        int ch = (ob % ROWB) >> 4;
        int sc = swz<COLS>(ch, r);
        gl2lds16(g + r * srcStride + sc * 8, lds + t * 512);
    }
}

// ---------------- 128x128 bf16 GEMM core, BK=64: C = Ap * Bp^T (both [rows, ld], K-contig) ----------------
template<int RELU, int OUTF, int OUTB>
__device__ __forceinline__ void gemm_core64(const bf16* __restrict__ Ap, const bf16* __restrict__ Bp,
                                            int ld, int Kloop,
                                            const float* __restrict__ bias, float scale,
                                            float* __restrict__ outf, bf16* __restrict__ outb,
                                            int N, int m0, int n0) {
    __shared__ bf16 As[128 * 64];
    __shared__ bf16 Bs[128 * 64];
    const int tid = threadIdx.x, wave = tid >> 6, lane = tid & 63;
    const int wr = wave >> 1, wc = wave & 1;
    const int quad = lane >> 4, lq = lane & 15;

    floatx4 acc[4][4] = {};

    for (int k0 = 0; k0 < Kloop; k0 += 64) {
        stage_tile_sw<128, 64>(As, Ap + k0, ld, wave, lane);
        stage_tile_sw<128, 64>(Bs, Bp + k0, ld, wave, lane);
        __syncthreads();
        #pragma unroll
        for (int kk = 0; kk < 2; kk++) {
            const int chs = ((kk * 4 + quad) ^ (lq & 7)) * 8;
            bf16x8 af[4], bfr[4];
            #pragma unroll
            for (int i = 0; i < 4; i++)
                af[i] = *(const bf16x8*)&As[(wr * 64 + i * 16 + lq) * 64 + chs];
            #pragma unroll
            for (int j = 0; j < 4; j++)
                bfr[j] = *(const bf16x8*)&Bs[(wc * 64 + j * 16 + lq) * 64 + chs];
            #pragma unroll
            for (int i = 0; i < 4; i++)
                #pragma unroll
                for (int j = 0; j < 4; j++)
                    acc[i][j] = __builtin_amdgcn_mfma_f32_16x16x32_bf16(af[i], bfr[j], acc[i][j], 0, 0, 0);
        }
        __syncthreads();
    }
    #pragma unroll
    for (int j = 0; j < 4; j++) {
        const int gc = n0 + wc * 64 + j * 16 + lq;
        const float bv = bias ? bias[gc] : 0.f;
        #pragma unroll
        for (int i = 0; i < 4; i++) {
            #pragma unroll
            for (int r = 0; r < 4; r++) {
                const int gr = m0 + wr * 64 + i * 16 + quad * 4 + r;
                float v = (acc[i][j][r] + bv) * scale;
                if (RELU) v = fmaxf(v, 0.f);
                if (OUTF) outf[(size_t)gr * N + gc] = v;
                if (OUTB) outb[(size_t)gr * N + gc] = (bf16)v;
            }
        }
    }
}

// W1 relu GEMM: M=4096,N=4096,K=1024; grid 1024, XCD-swizzled (4 m-tiles/XCD)
__global__ __launch_bounds__(256) void gemm_bf16relu(const bf16* A, const bf16* Bt, const float* bias,
                                                     bf16* out) {
    const int bid = blockIdx.x;
    const int xcd = bid & 7, j = bid >> 3;
    const int mt = xcd * 4 + (j >> 5);
    const int nt = j & 31;
    const int m0 = mt * 128, n0 = nt * 128;
    gemm_core64<1, 0, 1>(A + (size_t)m0 * 1024, Bt + (size_t)n0 * 1024, 1024, 1024,
                         bias, 1.f, nullptr, out, 4096, m0, n0);
}

// fused q,k,v projection; q pre-scaled by 0.125*log2e. grid 768, z-inner.
__global__ __launch_bounds__(256) void gemm_qkv(const bf16* A, const bf16* Wt,
                                                const float* bq, const float* bk, const float* bv,
                                                bf16* out) {
    const int bid = blockIdx.x;
    const int xcd = bid & 7, j = bid >> 3;
    const int mloc = j / 24, r = j % 24;
    const int z = r >> 3, nt = r & 7;
    const int m0 = (xcd * 4 + mloc) * 128, n0 = nt * 128;
    const bf16* Bt = Wt + (size_t)z * 1024 * 1024;
    const float* bias = (z == 0) ? bq : (z == 1) ? bk : bv;
    bf16* o = out + (size_t)z * 4096 * 1024;
    const float scale = (z == 0) ? 0.125f * LOG2E : 1.f;
    gemm_core64<0, 0, 1>(A + (size_t)m0 * 1024, Bt + (size_t)n0 * 1024, 1024, 1024,
                         bias, scale, nullptr, o, 1024, m0, n0);
}

// W2 split-K GEMM: M=4096, N=1024, K=4096 -> 2 halves of 2048. grid 512.
// bias folded into split 0; partials summed in ln3_kernel.
__global__ __launch_bounds__(256) void gemm_splitk(const bf16* __restrict__ A, const bf16* __restrict__ Bt,
                                                   const float* __restrict__ bias,
                                                   float* __restrict__ out0, float* __restrict__ out1) {
    const int bid = blockIdx.x;
    const int xcd = bid & 7, j = bid >> 3;          // j in [0,64)
    const int mloc = j >> 4, rem = j & 15;
    const int nt = rem >> 1, s = rem & 1;
    const int m0 = (xcd * 4 + mloc) * 128, n0 = nt * 128;
    const int ks = s * 2048;
    gemm_core64<0, 1, 0>(A + (size_t)m0 * 4096 + ks, Bt + (size_t)n0 * 4096 + ks, 4096, 2048,
                         s ? nullptr : bias, 1.f, s ? out1 : out0, nullptr, 1024, m0, n0);
}

// ---------------- 128x64-tile BK=64 GEMM for Wo (K=1024) ----------------
__global__ __launch_bounds__(256) void gemm_n1024(const bf16* __restrict__ A, const bf16* __restrict__ Bt,
                                                  const float* __restrict__ bias, float* __restrict__ out,
                                                  int K) {
    __shared__ bf16 As[128 * 64];
    __shared__ bf16 Bs[64 * 64];
    const int bid = blockIdx.x;
    const int xcd = bid & 7, j = bid >> 3;
    const int mt = xcd * 4 + (j >> 4);
    const int nt = j & 15;
    const int m0 = mt * 128, n0 = nt * 64;
    const int tid = threadIdx.x, wave = tid >> 6, lane = tid & 63;
    const int wr = wave >> 1, wc = wave & 1;
    const int quad = lane >> 4, lq = lane & 15;

    floatx4 acc[4][2] = {};
    const bf16* Ap = A + (size_t)m0 * K;
    const bf16* Bp = Bt + (size_t)n0 * K;

    for (int k0 = 0; k0 < K; k0 += 64) {
        stage_tile_sw<128, 64>(As, Ap + k0, K, wave, lane);
        stage_tile_sw<64, 64>(Bs, Bp + k0, K, wave, lane);
        __syncthreads();
        #pragma unroll
        for (int kk = 0; kk < 2; kk++) {
            const int chs = ((kk * 4 + quad) ^ (lq & 7)) * 8;
            bf16x8 af[4], bfr[2];
            #pragma unroll
            for (int i = 0; i < 4; i++)
                af[i] = *(const bf16x8*)&As[(wr * 64 + i * 16 + lq) * 64 + chs];
            #pragma unroll
            for (int jj = 0; jj < 2; jj++)
                bfr[jj] = *(const bf16x8*)&Bs[(wc * 32 + jj * 16 + lq) * 64 + chs];
            #pragma unroll
            for (int i = 0; i < 4; i++)
                #pragma unroll
                for (int jj = 0; jj < 2; jj++)
                    acc[i][jj] = __builtin_amdgcn_mfma_f32_16x16x32_bf16(af[i], bfr[jj], acc[i][jj], 0, 0, 0);
        }
        __syncthreads();
    }
    #pragma unroll
    for (int jj = 0; jj < 2; jj++) {
        const int gc = n0 + wc * 32 + jj * 16 + lq;
        const float bv = bias[gc];
        #pragma unroll
        for (int i = 0; i < 4; i++)
            #pragma unroll
            for (int r = 0; r < 4; r++) {
                const int gr = m0 + wr * 64 + i * 16 + quad * 4 + r;
                out[(size_t)gr * 1024 + gc] = acc[i][jj][r] + bv;
            }
    }
}

// ---------------- all-layer weight transpose+convert (one launch) ----------------
__device__ __forceinline__ void ttile(const float* __restrict__ src, bf16* __restrict__ dst,
                                      int K, int N, int n0, int k0) {
    __shared__ float t[32][33];
    const int tx = threadIdx.x & 31, ty = threadIdx.x >> 5;
    #pragma unroll
    for (int i = 0; i < 4; i++)
        t[ty + i * 8][tx] = src[(size_t)(k0 + ty + i * 8) * N + n0 + tx];
    __syncthreads();
    #pragma unroll
    for (int i = 0; i < 4; i++)
        dst[(size_t)(n0 + ty + i * 8) * K + k0 + tx] = (bf16)t[tx][ty + i * 8];
}

// per-layer arena (bf16 elems): qkvT 3*1048576 | oT 1048576 | w1T 4194304 | w2T 4194304
#define WT_LAYER 12582912
__global__ __launch_bounds__(256) void transpose_mega(const float* Wq, const float* Wk, const float* Wv,
                                                      const float* Wo, const float* W1, const float* W2,
                                                      bf16* WT) {
    const int bx = blockIdx.x;
    const int l = bx / 12288, r = bx % 12288;
    const size_t w1k = (size_t)l * 1048576, w4m = (size_t)l * 4194304;
    bf16* base = WT + (size_t)l * WT_LAYER;
    if (r < 4096) {
        const int z = r >> 10, tile = r & 1023;
        const float* s = (z == 0) ? Wq + w1k : (z == 1) ? Wk + w1k : (z == 2) ? Wv + w1k : Wo + w1k;
        bf16* d = base + (size_t)z * 1048576;
        ttile(s, d, 1024, 1024, (tile & 31) * 32, (tile >> 5) * 32);
    } else if (r < 8192) {
        const int tile = r - 4096;
        ttile(W1 + w4m, base + 4194304, 1024, 4096, (tile & 127) * 32, (tile >> 7) * 32);
    } else {
        const int tile = r - 8192;
        ttile(W2 + w4m, base + 8388608, 4096, 1024, (tile & 31) * 32, (tile >> 5) * 32);
    }
}

// v [4096, h*64+d] bf16 -> vT [bh][d][L] bf16
__global__ __launch_bounds__(256) void transpose_v(const bf16* v, bf16* vT) {
    __shared__ bf16 t[32][33];
    const int l0 = blockIdx.x * 32, d0 = blockIdx.y * 32, bh = blockIdx.z;
    const int b = bh >> 4, h = bh & 15;
    const int tx = threadIdx.x & 31, ty = threadIdx.x >> 5;
    #pragma unroll
    for (int i = 0; i < 4; i++)
        t[ty + i * 8][tx] = v[(size_t)(b * 1024 + l0 + ty + i * 8) * 1024 + h * 64 + d0 + tx];
    __syncthreads();
    #pragma unroll
    for (int i = 0; i < 4; i++)
        vT[((size_t)bh * 64 + d0 + ty + i * 8) * 1024 + l0 + tx] = t[tx][ty + i * 8];
}

__global__ __launch_bounds__(256) void cvt_f32_bf16(const float* src, bf16* dst) {
    const int i = (blockIdx.x * 256 + threadIdx.x) * 4;
    const float4 v = *(const float4*)(src + i);
    bf16 t4[4] = {(bf16)v.x, (bf16)v.y, (bf16)v.z, (bf16)v.w};
    *(uint64_t*)(dst + i) = *(const uint64_t*)t4;
}

// ---------------- LayerNorm over (sum of inputs); writes fp32 + bf16 ----------------
template<int NPART>
__device__ __forceinline__ void ln_body(const float* __restrict__ a0, const float* __restrict__ a1,
                                        const float* __restrict__ res,
                                        const float* __restrict__ gamma, const float* __restrict__ beta,
                                        float* __restrict__ outf, bf16* __restrict__ outb) {
    const int row = blockIdx.x, tid = threadIdx.x;
    const size_t base = (size_t)row * 1024 + tid * 4;
    const float4 av = *(const float4*)(a0 + base);
    const float4 rv = *(const float4*)(res + base);
    float x0 = av.x + rv.x, x1 = av.y + rv.y, x2 = av.z + rv.z, x3 = av.w + rv.w;
    if (NPART == 2) {
        const float4 bv = *(const float4*)(a1 + base);
        x0 += bv.x; x1 += bv.y; x2 += bv.z; x3 += bv.w;
    }
    float s  = x0 + x1 + x2 + x3;
    float sq = x0 * x0 + x1 * x1 + x2 * x2 + x3 * x3;
    #pragma unroll
    for (int off = 32; off; off >>= 1) {
        s  += __shfl_xor(s,  off, 64);
        sq += __shfl_xor(sq, off, 64);
    }
    __shared__ float red[8];
    const int wave = tid >> 6, lane = tid & 63;
    if (lane == 0) { red[wave] = s; red[wave + 4] = sq; }
    __syncthreads();
    const float S  = red[0] + red[1] + red[2] + red[3];
    const float SQ = red[4] + red[5] + red[6] + red[7];
    const float mean = S * (1.f / 1024.f);
    const float var  = SQ * (1.f / 1024.f) - mean * mean;
    const float rstd = rsqrtf(var + 1e-6f);
    const int c = tid * 4;
    const float4 g  = *(const float4*)(gamma + c);
    const float4 be = *(const float4*)(beta + c);
    float y0 = (x0 - mean) * rstd * g.x + be.x;
    float y1 = (x1 - mean) * rstd * g.y + be.y;
    float y2 = (x2 - mean) * rstd * g.z + be.z;
    float y3 = (x3 - mean) * rstd * g.w + be.w;
    float4 yo; yo.x = y0; yo.y = y1; yo.z = y2; yo.w = y3;
    *(float4*)(outf + base) = yo;
    bf16 t4[4] = {(bf16)y0, (bf16)y1, (bf16)y2, (bf16)y3};
    *(uint64_t*)(outb + base) = *(const uint64_t*)t4;
}

__global__ __launch_bounds__(256) void ln_kernel(const float* a, const float* res,
                                                 const float* gamma, const float* beta,
                                                 float* outf, bf16* outb) {
    ln_body<1>(a, nullptr, res, gamma, beta, outf, outb);
}

__global__ __launch_bounds__(256) void ln3_kernel(const float* a0, const float* a1, const float* res,
                                                  const float* gamma, const float* beta,
                                                  float* outf, bf16* outb) {
    ln_body<2>(a0, a1, res, gamma, beta, outf, outb);
}

// ---------------- flash attention (R2 version, verified) ----------------
__global__ __launch_bounds__(256, 2) void attn_kernel(const bf16* __restrict__ Q, const bf16* __restrict__ Kg,
                                                      const bf16* __restrict__ Vt, bf16* __restrict__ O) {
    __shared__ bf16 Ks[128 * 64];
    __shared__ bf16 Vs[64 * 128];
    __shared__ bf16 Ps[128 * 128];
    const int bh = blockIdx.x, qt = blockIdx.y;
    const int b = bh >> 4, h = bh & 15;
    const int tid = threadIdx.x, wave = tid >> 6, lane = tid & 63;
    const int quad = lane >> 4, lq = lane & 15;

    const bf16* qg = Q + ((size_t)b * 1024 + qt * 128) * 1024 + h * 64;
    const bf16* kg = Kg + (size_t)b * 1024 * 1024 + h * 64;
    const bf16* vg = Vt + (size_t)bh * 64 * 1024;

    stage_tile_sw<128, 64>(Ps, qg, 1024, wave, lane);
    __syncthreads();
    bf16x8 aq[2][2];
    #pragma unroll
    for (int i = 0; i < 2; i++)
        #pragma unroll
        for (int kk = 0; kk < 2; kk++) {
            const int row = wave * 32 + i * 16 + lq;
            const int chs = (kk * 4 + quad) ^ (lq & 7);
            aq[i][kk] = *(const bf16x8*)&Ps[row * 64 + chs * 8];
        }

    floatx4 oacc[2][4] = {};
    float lsum[2][4] = {};

    for (int kt = 0; kt < 1024; kt += 128) {
        stage_tile_sw<128, 64>(Ks, kg + (size_t)kt * 1024, 1024, wave, lane);
        stage_tile_sw<64, 128>(Vs, vg + kt, 1024, wave, lane);
        __syncthreads();

        floatx4 sacc[2][8] = {};
        #pragma unroll
        for (int kk = 0; kk < 2; kk++)
            #pragma unroll
            for (int j = 0; j < 8; j++) {
                const int chs = (kk * 4 + quad) ^ (lq & 7);
                bf16x8 bk = *(const bf16x8*)&Ks[(j * 16 + lq) * 64 + chs * 8];
                sacc[0][j] = __builtin_amdgcn_mfma_f32_16x16x32_bf16(aq[0][kk], bk, sacc[0][j], 0, 0, 0);
                sacc[1][j] = __builtin_amdgcn_mfma_f32_16x16x32_bf16(aq[1][kk], bk, sacc[1][j], 0, 0, 0);
            }

        #pragma unroll
        for (int i = 0; i < 2; i++)
            #pragma unroll
            for (int r = 0; r < 4; r++) {
                const int row = wave * 32 + i * 16 + quad * 4 + r;
                const int rb = row & 7;
                float ls = 0.f;
                #pragma unroll
                for (int j = 0; j < 8; j++) {
                    const float pv = exp2f(sacc[i][j][r]);
                    ls += pv;
                    const int col = j * 16 + lq;
                    Ps[row * 128 + ((col >> 3) ^ rb) * 8 + (col & 7)] = (bf16)pv;
                }
                lsum[i][r] += ls;
            }

        #pragma unroll
        for (int kk = 0; kk < 4; kk++) {
            bf16x8 ap[2];
            #pragma unroll
            for (int i = 0; i < 2; i++) {
                const int row = wave * 32 + i * 16 + lq;
                const int chs = (kk * 4 + quad) ^ (lq & 7);
                ap[i] = *(const bf16x8*)&Ps[row * 128 + chs * 8];
            }
            #pragma unroll
            for (int dj = 0; dj < 4; dj++) {
                const int chs = (kk * 4 + quad) ^ (lq & 7);
                bf16x8 bv = *(const bf16x8*)&Vs[(dj * 16 + lq) * 128 + chs * 8];
                oacc[0][dj] = __builtin_amdgcn_mfma_f32_16x16x32_bf16(ap[0], bv, oacc[0][dj], 0, 0, 0);
                oacc[1][dj] = __builtin_amdgcn_mfma_f32_16x16x32_bf16(ap[1], bv, oacc[1][dj], 0, 0, 0);
            }
        }
        __syncthreads();
    }

    #pragma unroll
    for (int i = 0; i < 2; i++)
        #pragma unroll
        for (int r = 0; r < 4; r++) {
            float l = lsum[i][r];
            l += __shfl_xor(l, 1, 64); l += __shfl_xor(l, 2, 64);
            l += __shfl_xor(l, 4, 64); l += __shfl_xor(l, 8, 64);
            lsum[i][r] = 1.f / l;
        }
    #pragma unroll
    for (int i = 0; i < 2; i++)
        #pragma unroll
        for (int dj = 0; dj < 4; dj++)
            #pragma unroll
            for (int r = 0; r < 4; r++) {
                const int row = qt * 128 + wave * 32 + i * 16 + quad * 4 + r;
                O[((size_t)b * 1024 + row) * 1024 + h * 64 + dj * 16 + lq] = (bf16)(oacc[i][dj][r] * lsum[i][r]);
            }
}

// ---------------- host ----------------
extern "C" void kernel_launch(void* const* d_in, const int* in_sizes, int n_in,
                              void* d_out, int out_size, void* d_ws, size_t ws_size,
                              hipStream_t stream) {
    const float* queries = (const float*)d_in[0];
    const float* Wq = (const float*)d_in[1];  const float* bq = (const float*)d_in[2];
    const float* Wk = (const float*)d_in[3];  const float* bk = (const float*)d_in[4];
    const float* Wv = (const float*)d_in[5];  const float* bv = (const float*)d_in[6];
    const float* Wo = (const float*)d_in[7];  const float* bo = (const float*)d_in[8];
    const float* ln1_s = (const float*)d_in[9];   const float* ln1_b = (const float*)d_in[10];
    const float* ln2_s = (const float*)d_in[11];  const float* ln2_b = (const float*)d_in[12];
    const float* W1 = (const float*)d_in[13]; const float* b1 = (const float*)d_in[14];
    const float* W2 = (const float*)d_in[15]; const float* b2 = (const float*)d_in[16];

    char* p = (char*)d_ws;
    size_t off = 0;
    auto take = [&](size_t bytes) { void* r = p + off; off += bytes; return r; };
    bf16*  WT    = (bf16*)take((size_t)4 * WT_LAYER * 2);   // 96 MB: all layers' transposed weights
    bf16*  x_bf  = (bf16*)take(8388608);
    float* xf    = (float*)take(16777216);
    bf16*  qkvb  = (bf16*)take(25165824);
    bf16*  vTb   = (bf16*)take(8388608);
    bf16*  updb  = (bf16*)take(8388608);
    float* az0   = (float*)take(16777216);
    float* az1   = (float*)take(16777216);
    float* hf    = (float*)take(16777216);
    bf16*  hbf   = (bf16*)take(8388608);
    bf16*  tmlp  = (bf16*)take(33554432);

    transpose_mega<<<49152, 256, 0, stream>>>(Wq, Wk, Wv, Wo, W1, W2, WT);
    cvt_f32_bf16<<<4096, 256, 0, stream>>>(queries, x_bf);

    for (int l = 0; l < 4; ++l) {
        bf16* base  = WT + (size_t)l * WT_LAYER;
        bf16* WqkvT = base;
        bf16* WoT   = base + 3145728;
        bf16* W1T   = base + 4194304;
        bf16* W2T   = base + 8388608;

        gemm_qkv<<<768, 256, 0, stream>>>(x_bf, WqkvT,
                                          bq + l * 1024, bk + l * 1024, bv + l * 1024, qkvb);
        transpose_v<<<dim3(32, 2, 64), 256, 0, stream>>>(qkvb + 2 * 4194304, vTb);
        attn_kernel<<<dim3(64, 8), 256, 0, stream>>>(qkvb, qkvb + 4194304, vTb, updb);
        gemm_n1024<<<512, 256, 0, stream>>>(updb, WoT, bo + l * 1024, az0, 1024);
        ln_kernel<<<4096, 256, 0, stream>>>(az0, (l == 0) ? queries : xf,
                                            ln1_s + l * 1024, ln1_b + l * 1024, hf, hbf);
        gemm_bf16relu<<<1024, 256, 0, stream>>>(hbf, W1T, b1 + l * 4096, tmlp);
        gemm_splitk<<<512, 256, 0, stream>>>(tmlp, W2T, b2 + l * 1024, az0, az1);
        ln3_kernel<<<4096, 256, 0, stream>>>(az0, az1, hf, ln2_s + l * 1024, ln2_b + l * 1024,
                                             (l == 3) ? (float*)d_out : xf, x_bf);
    }
}